// Round 8
// baseline (452.526 us; speedup 1.0000x reference)
//
#include <hip/hip_runtime.h>

typedef float v4f __attribute__((ext_vector_type(4)));
typedef short v8s __attribute__((ext_vector_type(8)));

#define ALPHA 0.2f
#define LOG2E 1.44269504088896340736f
#define NROW 8192
#define FIN 256
#define FOUT 64
#define JSPLIT 8
#define JCHUNK (NROW / JSPLIT) /* 1024 */
#define NSTEP (JCHUNK / 32)    /* 32 */

static __device__ __forceinline__ unsigned short f2bf(float f) {
  unsigned int u = __builtin_bit_cast(unsigned int, f);
  u += 0x7fff + ((u >> 16) & 1);
  return (unsigned short)(u >> 16);
}
static __device__ __forceinline__ float bf2f(unsigned short s) {
  unsigned int u = ((unsigned int)s) << 16;
  return __builtin_bit_cast(float, u);
}

// ---- Kernel 1: Wh = h@W -> whT tiled [j/32][64][32] bf16; src, dst --------
__global__ __launch_bounds__(256) void k1_proj(
    const float* __restrict__ h, const float* __restrict__ edge,
    const float* __restrict__ W, const float* __restrict__ a,
    const float* __restrict__ We, unsigned short* __restrict__ whT,
    float* __restrict__ srcv, float* __restrict__ dstv) {
  __shared__ float Ws[FIN * FOUT];
  int tid = threadIdx.x;
  const float4* Wg = (const float4*)W;
  float4* Wl = (float4*)Ws;
#pragma unroll
  for (int it = 0; it < 16; ++it) Wl[it * 256 + tid] = Wg[it * 256 + tid];
  int lane = tid & 63;
  int wave = tid >> 6;
  float a1c = a[lane], a2c = a[64 + lane], a3c = a[128 + lane];
  float Wer[8];
#pragma unroll
  for (int k = 0; k < 8; ++k) Wer[k] = We[k * 64 + lane];
  __syncthreads();
  int rbase = blockIdx.x * 16 + wave * 4;
  const float* hr0 = h + (long)(rbase + 0) * FIN;
  const float* hr1 = h + (long)(rbase + 1) * FIN;
  const float* hr2 = h + (long)(rbase + 2) * FIN;
  const float* hr3 = h + (long)(rbase + 3) * FIN;
  float acc0 = 0.f, acc1 = 0.f, acc2 = 0.f, acc3 = 0.f;
#pragma unroll 2
  for (int k = 0; k < FIN; k += 4) {
    float4 h0 = *(const float4*)(hr0 + k);
    float4 h1 = *(const float4*)(hr1 + k);
    float4 h2 = *(const float4*)(hr2 + k);
    float4 h3 = *(const float4*)(hr3 + k);
#pragma unroll
    for (int t = 0; t < 4; ++t) {
      float w = Ws[(k + t) * 64 + lane];
      float e0 = (t == 0) ? h0.x : (t == 1) ? h0.y : (t == 2) ? h0.z : h0.w;
      float e1 = (t == 0) ? h1.x : (t == 1) ? h1.y : (t == 2) ? h1.z : h1.w;
      float e2 = (t == 0) ? h2.x : (t == 1) ? h2.y : (t == 2) ? h2.z : h2.w;
      float e3 = (t == 0) ? h3.x : (t == 1) ? h3.y : (t == 2) ? h3.z : h3.w;
      acc0 = __builtin_fmaf(e0, w, acc0);
      acc1 = __builtin_fmaf(e1, w, acc1);
      acc2 = __builtin_fmaf(e2, w, acc2);
      acc3 = __builtin_fmaf(e3, w, acc3);
    }
  }
#pragma unroll
  for (int rr = 0; rr < 4; ++rr) {
    int r = rbase + rr;
    float acc = (rr == 0) ? acc0 : (rr == 1) ? acc1 : (rr == 2) ? acc2 : acc3;
    float4 e0 = *(const float4*)(edge + r * 8);
    float4 e1 = *(const float4*)(edge + r * 8 + 4);
    float aedge = e0.x * Wer[0] + e0.y * Wer[1] + e0.z * Wer[2] +
                  e0.w * Wer[3] + e1.x * Wer[4] + e1.y * Wer[5] +
                  e1.z * Wer[6] + e1.w * Wer[7];
    float ps = acc * a1c + aedge * a3c;
    float pd = acc * a2c;
#pragma unroll
    for (int off = 32; off >= 1; off >>= 1) {
      ps += __shfl_xor(ps, off);
      pd += __shfl_xor(pd, off);
    }
    // tiled layout: whT[(j>>5)*2048 + fout*32 + (j&31)]
    whT[((long)(r >> 5)) * 2048 + lane * 32 + (r & 31)] = f2bf(acc);
    if (lane == 0) {
      srcv[r] = ps;
      dstv[r] = pd;
    }
  }
}

// ---------------- Kernel 1b: global max of dst ----------------------------
__global__ __launch_bounds__(256) void k1b_dstmax(const float* __restrict__ dstv,
                                                  float* __restrict__ dmax) {
  int tid = threadIdx.x;
  float m = -1e30f;
  for (int k = tid; k < NROW; k += 256) m = fmaxf(m, dstv[k]);
#pragma unroll
  for (int off = 32; off >= 1; off >>= 1) m = fmaxf(m, __shfl_xor(m, off));
  __shared__ float red[4];
  if ((tid & 63) == 0) red[tid >> 6] = m;
  __syncthreads();
  if (tid == 0) dmax[0] = fmaxf(fmaxf(red[0], red[1]), fmaxf(red[2], red[3]));
}

// ---------------- Kernel 2: fused masked-softmax-weight x Wh (MFMA) -------
// adj (HBM, ~900cy) prefetched 2 steps ahead; dstv/whT (L2, ~200cy) 1 step.
struct AdjB {
  int4 a0, a1;
};
struct DWB {
  float4 d0, d1;
  v8s b0, b1, b2, b3;
};

static __device__ __forceinline__ void adjload(AdjB& A,
                                               const int* __restrict__ adj,
                                               long rowbase, int g, int jj) {
  const int* ap = adj + rowbase + jj + g * 8;
  A.a0 = *(const int4*)ap;
  A.a1 = *(const int4*)(ap + 4);
}

static __device__ __forceinline__ void dwload(DWB& D,
                                              const float* __restrict__ dstv,
                                              const unsigned short* __restrict__ whT,
                                              int g, int m, int jj) {
  const float* dp = dstv + jj + g * 8;
  D.d0 = *(const float4*)dp;
  D.d1 = *(const float4*)(dp + 4);
  // tiled whT: tile (jj>>5) is 2048 shorts; fragment c at +c*512; each of
  // the 4 loads below covers a contiguous 1KB across the wave's 64 lanes.
  const unsigned short* wp = whT + ((long)(jj >> 5)) * 2048 + m * 32 + g * 8;
  D.b0 = *(const v8s*)(wp + 0);
  D.b1 = *(const v8s*)(wp + 512);
  D.b2 = *(const v8s*)(wp + 1024);
  D.b3 = *(const v8s*)(wp + 1536);
}

static __device__ __forceinline__ void computestep(const AdjB& A, const DWB& D,
                                                   float sv, float M2, v4f& a0,
                                                   v4f& a1, v4f& a2, v4f& a3,
                                                   float& ssum) {
  v8s aw;
#define WCALC(adji, dsti, slot)                                 \
  {                                                             \
    float x = sv + (dsti);                                      \
    float lr = fmaxf(x, ALPHA * x);                             \
    float w = exp2f(__builtin_fmaf(lr, LOG2E, -M2));            \
    unsigned short wb = ((adji) > 0) ? f2bf(w) : (unsigned short)0; \
    ssum += bf2f(wb);                                           \
    aw[slot] = (short)wb;                                       \
  }
  WCALC(A.a0.x, D.d0.x, 0)
  WCALC(A.a0.y, D.d0.y, 1)
  WCALC(A.a0.z, D.d0.z, 2)
  WCALC(A.a0.w, D.d0.w, 3)
  WCALC(A.a1.x, D.d1.x, 4)
  WCALC(A.a1.y, D.d1.y, 5)
  WCALC(A.a1.z, D.d1.z, 6)
  WCALC(A.a1.w, D.d1.w, 7)
#undef WCALC
  a0 = __builtin_amdgcn_mfma_f32_16x16x32_bf16(aw, D.b0, a0, 0, 0, 0);
  a1 = __builtin_amdgcn_mfma_f32_16x16x32_bf16(aw, D.b1, a1, 0, 0, 0);
  a2 = __builtin_amdgcn_mfma_f32_16x16x32_bf16(aw, D.b2, a2, 0, 0, 0);
  a3 = __builtin_amdgcn_mfma_f32_16x16x32_bf16(aw, D.b3, a3, 0, 0, 0);
}

__global__ __launch_bounds__(256) void k2_attn(
    const int* __restrict__ adj, const float* __restrict__ srcg,
    const float* __restrict__ dstv, const float* __restrict__ dmax,
    const unsigned short* __restrict__ whT, float* __restrict__ hpart,
    float* __restrict__ spart) {
  int tid = threadIdx.x;
  int lane = tid & 63;
  int wave = tid >> 6;
  int rtile = blockIdx.x * 64 + wave * 16;
  int jy = blockIdx.y;
  int jbase = jy * JCHUNK;
  int m = lane & 15;
  int g = lane >> 4;
  int row = rtile + m;
  long rowbase = (long)row * NROW;
  float sv = srcg[row];
  float dm = dmax[0];
  float xm = sv + dm;
  float M2 = fmaxf(xm, ALPHA * xm) * LOG2E;
  v4f a0 = {}, a1 = {}, a2 = {}, a3 = {};
  float ssum = 0.f;
  AdjB A0, A1;
  DWB D0, D1;
  adjload(A0, adj, rowbase, g, jbase + 0 * 32);
  adjload(A1, adj, rowbase, g, jbase + 1 * 32);
  dwload(D0, dstv, whT, g, m, jbase + 0 * 32);
  for (int t = 0; t < NSTEP; t += 2) {
    dwload(D1, dstv, whT, g, m, jbase + (t + 1) * 32);
    computestep(A0, D0, sv, M2, a0, a1, a2, a3, ssum);
    if (t + 2 < NSTEP) {
      adjload(A0, adj, rowbase, g, jbase + (t + 2) * 32);  // 2-step lead
      dwload(D0, dstv, whT, g, m, jbase + (t + 2) * 32);
    }
    computestep(A1, D1, sv, M2, a0, a1, a2, a3, ssum);
    if (t + 3 < NSTEP)
      adjload(A1, adj, rowbase, g, jbase + (t + 3) * 32);  // 2-step lead
  }
  // row-sum: combine the 4 k-groups (lanes with same (lane&15))
  ssum += __shfl_xor(ssum, 16);
  ssum += __shfl_xor(ssum, 32);
  if (g == 0) spart[jy * NROW + row] = ssum;
  // store partial numerator tile: D row=(g*4+r), col=ct*16+m
  float* hp = hpart + ((long)jy * NROW + rtile) * FOUT;
#pragma unroll
  for (int r = 0; r < 4; ++r) {
    hp[(g * 4 + r) * FOUT + 0 + m] = a0[r];
    hp[(g * 4 + r) * FOUT + 16 + m] = a1[r];
    hp[(g * 4 + r) * FOUT + 32 + m] = a2[r];
    hp[(g * 4 + r) * FOUT + 48 + m] = a3[r];
  }
}

// ---------------- Kernel 3: combine partials, divide, ELU (float4) --------
__global__ __launch_bounds__(256) void k3_fin(const float* __restrict__ hpart,
                                              const float* __restrict__ spart,
                                              float* __restrict__ out) {
  long g4 = (long)blockIdx.x * 256 + threadIdx.x;  // float4 index
  long base = g4 * 4;
  int i = (int)(base >> 6);  // all 4 elements in same row (4 | base, 64 | row)
  float4 num = {0.f, 0.f, 0.f, 0.f};
  float den = 0.f;
#pragma unroll
  for (int p = 0; p < JSPLIT; ++p) {
    float4 v = *(const float4*)(hpart + (long)p * NROW * FOUT + base);
    num.x += v.x;
    num.y += v.y;
    num.z += v.z;
    num.w += v.w;
    den += spart[p * NROW + i];
  }
  float rd = 1.0f / den;
  float4 o;
  o.x = num.x * rd;
  o.y = num.y * rd;
  o.z = num.z * rd;
  o.w = num.w * rd;
  o.x = o.x > 0.f ? o.x : (__expf(o.x) - 1.0f);
  o.y = o.y > 0.f ? o.y : (__expf(o.y) - 1.0f);
  o.z = o.z > 0.f ? o.z : (__expf(o.z) - 1.0f);
  o.w = o.w > 0.f ? o.w : (__expf(o.w) - 1.0f);
  *(float4*)(out + base) = o;
}

extern "C" void kernel_launch(void* const* d_in, const int* in_sizes, int n_in,
                              void* d_out, int out_size, void* d_ws,
                              size_t ws_size, hipStream_t stream) {
  const float* h = (const float*)d_in[0];
  const float* edge = (const float*)d_in[1];
  const int* adj = (const int*)d_in[2];
  const float* W = (const float*)d_in[3];
  const float* a = (const float*)d_in[4];
  const float* We = (const float*)d_in[5];
  float* out = (float*)d_out;
  char* ws = (char*)d_ws;
  unsigned short* whT = (unsigned short*)ws;           // 1 MB (tiled)
  float* srcv = (float*)(ws + 1048576);                // 32 KB
  float* dstv = (float*)(ws + 1081344);                // 32 KB
  float* dmax = (float*)(ws + 1114112);                // pad to 256B
  float* spart = (float*)(ws + 1114368);               // 256 KB
  float* hpart = (float*)(ws + 1376512);               // 16 MB
  hipLaunchKernelGGL(k1_proj, dim3(512), dim3(256), 0, stream, h, edge, W, a,
                     We, whT, srcv, dstv);
  hipLaunchKernelGGL(k1b_dstmax, dim3(1), dim3(256), 0, stream, dstv, dmax);
  hipLaunchKernelGGL(k2_attn, dim3(128, JSPLIT), dim3(256), 0, stream, adj,
                     srcv, dstv, dmax, whT, hpart, spart);
  hipLaunchKernelGGL(k3_fin, dim3(512), dim3(256), 0, stream, hpart, spart,
                     out);
}

// Round 11
// 419.144 us; speedup vs baseline: 1.0796x; 1.0796x over previous
//
#include <hip/hip_runtime.h>

typedef float v4f __attribute__((ext_vector_type(4)));
typedef short v8s __attribute__((ext_vector_type(8)));
typedef int v4i __attribute__((ext_vector_type(4)));

#define ALPHA 0.2f
#define LOG2E 1.44269504088896340736f
#define NROW 8192
#define FIN 256
#define FOUT 64
#define COLS_PER_WAVE 2048
#define NSTEP2 (COLS_PER_WAVE / 32) /* 64 */

static __device__ __forceinline__ unsigned short f2bf(float f) {
  unsigned int u = __builtin_bit_cast(unsigned int, f);
  u += 0x7fff + ((u >> 16) & 1);
  return (unsigned short)(u >> 16);
}
static __device__ __forceinline__ float bf2f(unsigned short s) {
  unsigned int u = ((unsigned int)s) << 16;
  return __builtin_bit_cast(float, u);
}

// ---- Kernel 1: Wh = h@W -> whT tiled [j/32][64][32] bf16; src, dst --------
__global__ __launch_bounds__(256) void k1_proj(
    const float* __restrict__ h, const float* __restrict__ edge,
    const float* __restrict__ W, const float* __restrict__ a,
    const float* __restrict__ We, unsigned short* __restrict__ whT,
    float* __restrict__ srcv, float* __restrict__ dstv) {
  __shared__ float Ws[FIN * FOUT];
  int tid = threadIdx.x;
  const float4* Wg = (const float4*)W;
  float4* Wl = (float4*)Ws;
#pragma unroll
  for (int it = 0; it < 16; ++it) Wl[it * 256 + tid] = Wg[it * 256 + tid];
  int lane = tid & 63;
  int wave = tid >> 6;
  float a1c = a[lane], a2c = a[64 + lane], a3c = a[128 + lane];
  float Wer[8];
#pragma unroll
  for (int k = 0; k < 8; ++k) Wer[k] = We[k * 64 + lane];
  __syncthreads();
  int rbase = blockIdx.x * 16 + wave * 4;
  const float* hr0 = h + (long)(rbase + 0) * FIN;
  const float* hr1 = h + (long)(rbase + 1) * FIN;
  const float* hr2 = h + (long)(rbase + 2) * FIN;
  const float* hr3 = h + (long)(rbase + 3) * FIN;
  float acc0 = 0.f, acc1 = 0.f, acc2 = 0.f, acc3 = 0.f;
#pragma unroll 2
  for (int k = 0; k < FIN; k += 4) {
    float4 h0 = *(const float4*)(hr0 + k);
    float4 h1 = *(const float4*)(hr1 + k);
    float4 h2 = *(const float4*)(hr2 + k);
    float4 h3 = *(const float4*)(hr3 + k);
#pragma unroll
    for (int t = 0; t < 4; ++t) {
      float w = Ws[(k + t) * 64 + lane];
      float e0 = (t == 0) ? h0.x : (t == 1) ? h0.y : (t == 2) ? h0.z : h0.w;
      float e1 = (t == 0) ? h1.x : (t == 1) ? h1.y : (t == 2) ? h1.z : h1.w;
      float e2 = (t == 0) ? h2.x : (t == 1) ? h2.y : (t == 2) ? h2.z : h2.w;
      float e3 = (t == 0) ? h3.x : (t == 1) ? h3.y : (t == 2) ? h3.z : h3.w;
      acc0 = __builtin_fmaf(e0, w, acc0);
      acc1 = __builtin_fmaf(e1, w, acc1);
      acc2 = __builtin_fmaf(e2, w, acc2);
      acc3 = __builtin_fmaf(e3, w, acc3);
    }
  }
#pragma unroll
  for (int rr = 0; rr < 4; ++rr) {
    int r = rbase + rr;
    float acc = (rr == 0) ? acc0 : (rr == 1) ? acc1 : (rr == 2) ? acc2 : acc3;
    float4 e0 = *(const float4*)(edge + r * 8);
    float4 e1 = *(const float4*)(edge + r * 8 + 4);
    float aedge = e0.x * Wer[0] + e0.y * Wer[1] + e0.z * Wer[2] +
                  e0.w * Wer[3] + e1.x * Wer[4] + e1.y * Wer[5] +
                  e1.z * Wer[6] + e1.w * Wer[7];
    float ps = acc * a1c + aedge * a3c;
    float pd = acc * a2c;
#pragma unroll
    for (int off = 32; off >= 1; off >>= 1) {
      ps += __shfl_xor(ps, off);
      pd += __shfl_xor(pd, off);
    }
    // tiled layout: whT[(j>>5)*2048 + fout*32 + (j&31)]
    whT[((long)(r >> 5)) * 2048 + lane * 32 + (r & 31)] = f2bf(acc);
    if (lane == 0) {
      srcv[r] = ps;
      dstv[r] = pd;
    }
  }
}

// ---------------- Kernel 1b: global max of dst ----------------------------
__global__ __launch_bounds__(256) void k1b_dstmax(const float* __restrict__ dstv,
                                                  float* __restrict__ dmax) {
  int tid = threadIdx.x;
  float m = -1e30f;
  for (int k = tid; k < NROW; k += 256) m = fmaxf(m, dstv[k]);
#pragma unroll
  for (int off = 32; off >= 1; off >>= 1) m = fmaxf(m, __shfl_xor(m, off));
  __shared__ float red[4];
  if ((tid & 63) == 0) red[tid >> 6] = m;
  __syncthreads();
  if (tid == 0) dmax[0] = fmaxf(fmaxf(red[0], red[1]), fmaxf(red[2], red[3]));
}

// ---- Kernel 2: fused masked-softmax-weight x Wh (MFMA), full-row blocks ---
// Block = 16 rows x all 8192 cols; wave w owns cols [w*2048,(w+1)*2048).
// Partials combined in LDS; div+ELU+store fused (no hpart/spart/k3).
// adj streamed with nontemporal (slc) loads to protect whT/dstv L2 residency.
struct AdjB {
  v4i a0, a1;
};
struct DWB {
  float4 d0, d1;
  v8s b0, b1, b2, b3;
};

static __device__ __forceinline__ void adjload(AdjB& A,
                                               const int* __restrict__ adj,
                                               long rowbase, int g, int jj) {
  const v4i* ap = (const v4i*)(adj + rowbase + jj + g * 8);
  A.a0 = __builtin_nontemporal_load(ap);
  A.a1 = __builtin_nontemporal_load(ap + 1);
}

static __device__ __forceinline__ void dwload(DWB& D,
                                              const float* __restrict__ dstv,
                                              const unsigned short* __restrict__ whT,
                                              int g, int m, int jj) {
  const float* dp = dstv + jj + g * 8;
  D.d0 = *(const float4*)dp;
  D.d1 = *(const float4*)(dp + 4);
  // tiled whT: tile (jj>>5) is 2048 shorts; fragment c at +c*512; each of
  // the 4 loads below covers a contiguous 1KB across the wave's 64 lanes.
  const unsigned short* wp = whT + ((long)(jj >> 5)) * 2048 + m * 32 + g * 8;
  D.b0 = *(const v8s*)(wp + 0);
  D.b1 = *(const v8s*)(wp + 512);
  D.b2 = *(const v8s*)(wp + 1024);
  D.b3 = *(const v8s*)(wp + 1536);
}

static __device__ __forceinline__ void computestep(const AdjB& A, const DWB& D,
                                                   float sv, float M2, v4f& a0,
                                                   v4f& a1, v4f& a2, v4f& a3,
                                                   float& ssum) {
  v8s aw;
#define WCALC(adji, dsti, slot)                                 \
  {                                                             \
    float x = sv + (dsti);                                      \
    float lr = fmaxf(x, ALPHA * x);                             \
    float w = exp2f(__builtin_fmaf(lr, LOG2E, -M2));            \
    unsigned short wb = ((adji) > 0) ? f2bf(w) : (unsigned short)0; \
    ssum += bf2f(wb);                                           \
    aw[slot] = (short)wb;                                       \
  }
  WCALC(A.a0[0], D.d0.x, 0)
  WCALC(A.a0[1], D.d0.y, 1)
  WCALC(A.a0[2], D.d0.z, 2)
  WCALC(A.a0[3], D.d0.w, 3)
  WCALC(A.a1[0], D.d1.x, 4)
  WCALC(A.a1[1], D.d1.y, 5)
  WCALC(A.a1[2], D.d1.z, 6)
  WCALC(A.a1[3], D.d1.w, 7)
#undef WCALC
  a0 = __builtin_amdgcn_mfma_f32_16x16x32_bf16(aw, D.b0, a0, 0, 0, 0);
  a1 = __builtin_amdgcn_mfma_f32_16x16x32_bf16(aw, D.b1, a1, 0, 0, 0);
  a2 = __builtin_amdgcn_mfma_f32_16x16x32_bf16(aw, D.b2, a2, 0, 0, 0);
  a3 = __builtin_amdgcn_mfma_f32_16x16x32_bf16(aw, D.b3, a3, 0, 0, 0);
}

__global__ __launch_bounds__(256) void k2_attn(
    const int* __restrict__ adj, const float* __restrict__ srcg,
    const float* __restrict__ dstv, const float* __restrict__ dmax,
    const unsigned short* __restrict__ whT, float* __restrict__ out) {
  __shared__ float nums[4][16][68];  // pad 64->68: conflict-free writes
  __shared__ float dens[4][16];
  int tid = threadIdx.x;
  int lane = tid & 63;
  int wave = tid >> 6;
  int rtile = blockIdx.x * 16;
  int jbase = wave * COLS_PER_WAVE;
  int m = lane & 15;
  int g = lane >> 4;
  int row = rtile + m;
  long rowbase = (long)row * NROW;
  float sv = srcg[row];
  float dm = dmax[0];
  float xm = sv + dm;
  float M2 = fmaxf(xm, ALPHA * xm) * LOG2E;
  v4f a0 = {}, a1 = {}, a2 = {}, a3 = {};
  float ssum = 0.f;
  AdjB A0, A1;
  DWB D0, D1;
  adjload(A0, adj, rowbase, g, jbase + 0 * 32);
  adjload(A1, adj, rowbase, g, jbase + 1 * 32);
  dwload(D0, dstv, whT, g, m, jbase + 0 * 32);
  for (int t = 0; t < NSTEP2; t += 2) {
    dwload(D1, dstv, whT, g, m, jbase + (t + 1) * 32);
    computestep(A0, D0, sv, M2, a0, a1, a2, a3, ssum);
    if (t + 2 < NSTEP2) {
      adjload(A0, adj, rowbase, g, jbase + (t + 2) * 32);
      dwload(D0, dstv, whT, g, m, jbase + (t + 2) * 32);
    }
    computestep(A1, D1, sv, M2, a0, a1, a2, a3, ssum);
    if (t + 3 < NSTEP2)
      adjload(A1, adj, rowbase, g, jbase + (t + 3) * 32);
  }
  // row-sum across the 4 k-groups
  ssum += __shfl_xor(ssum, 16);
  ssum += __shfl_xor(ssum, 32);
  if (g == 0) dens[wave][m] = ssum;
  // D layout: row=(g*4+r), col=ct*16+m
#pragma unroll
  for (int r = 0; r < 4; ++r) {
    nums[wave][g * 4 + r][0 + m] = a0[r];
    nums[wave][g * 4 + r][16 + m] = a1[r];
    nums[wave][g * 4 + r][32 + m] = a2[r];
    nums[wave][g * 4 + r][48 + m] = a3[r];
  }
  __syncthreads();
  // combine 4 wave-partials, divide, ELU, store: thread -> 4 consecutive cols
  int orow = tid >> 4;
  int ocol = (tid & 15) * 4;
  float4 n = {0.f, 0.f, 0.f, 0.f};
  float den = 0.f;
#pragma unroll
  for (int w = 0; w < 4; ++w) {
    float4 v = *(const float4*)&nums[w][orow][ocol];
    n.x += v.x;
    n.y += v.y;
    n.z += v.z;
    n.w += v.w;
    den += dens[w][orow];
  }
  float rd = 1.0f / den;
  float4 o;
  o.x = n.x * rd;
  o.y = n.y * rd;
  o.z = n.z * rd;
  o.w = n.w * rd;
  o.x = o.x > 0.f ? o.x : (__expf(o.x) - 1.0f);
  o.y = o.y > 0.f ? o.y : (__expf(o.y) - 1.0f);
  o.z = o.z > 0.f ? o.z : (__expf(o.z) - 1.0f);
  o.w = o.w > 0.f ? o.w : (__expf(o.w) - 1.0f);
  *(float4*)(out + (long)(rtile + orow) * FOUT + ocol) = o;
}

extern "C" void kernel_launch(void* const* d_in, const int* in_sizes, int n_in,
                              void* d_out, int out_size, void* d_ws,
                              size_t ws_size, hipStream_t stream) {
  const float* h = (const float*)d_in[0];
  const float* edge = (const float*)d_in[1];
  const int* adj = (const int*)d_in[2];
  const float* W = (const float*)d_in[3];
  const float* a = (const float*)d_in[4];
  const float* We = (const float*)d_in[5];
  float* out = (float*)d_out;
  char* ws = (char*)d_ws;
  unsigned short* whT = (unsigned short*)ws;           // 1 MB (tiled)
  float* srcv = (float*)(ws + 1048576);                // 32 KB
  float* dstv = (float*)(ws + 1081344);                // 32 KB
  float* dmax = (float*)(ws + 1114112);                // pad to 256B
  hipLaunchKernelGGL(k1_proj, dim3(512), dim3(256), 0, stream, h, edge, W, a,
                     We, whT, srcv, dstv);
  hipLaunchKernelGGL(k1b_dstmax, dim3(1), dim3(256), 0, stream, dstv, dmax);
  hipLaunchKernelGGL(k2_attn, dim3(512), dim3(256), 0, stream, adj, srcv, dstv,
                     dmax, whT, out);
}

// Round 14
// 418.382 us; speedup vs baseline: 1.0816x; 1.0018x over previous
//
#include <hip/hip_runtime.h>

typedef float v4f __attribute__((ext_vector_type(4)));
typedef short v8s __attribute__((ext_vector_type(8)));
typedef int v4i __attribute__((ext_vector_type(4)));

#define ALPHA 0.2f
#define LOG2E 1.44269504088896340736f
#define NROW 8192
#define FIN 256
#define FOUT 64
#define NWAVES 4
#define NSTEP2 (NROW / 32 / NWAVES) /* 64 */

static __device__ __forceinline__ unsigned short f2bf(float f) {
  unsigned int u = __builtin_bit_cast(unsigned int, f);
  u += 0x7fff + ((u >> 16) & 1);
  return (unsigned short)(u >> 16);
}
static __device__ __forceinline__ float bf2f(unsigned short s) {
  unsigned int u = ((unsigned int)s) << 16;
  return __builtin_bit_cast(float, u);
}

// ---- Kernel 1: Wh = h@W -> whT tiled [j/32][64][32] bf16; src, dst --------
__global__ __launch_bounds__(256) void k1_proj(
    const float* __restrict__ h, const float* __restrict__ edge,
    const float* __restrict__ W, const float* __restrict__ a,
    const float* __restrict__ We, unsigned short* __restrict__ whT,
    float* __restrict__ srcv, float* __restrict__ dstv) {
  __shared__ float Ws[FIN * FOUT];
  int tid = threadIdx.x;
  const float4* Wg = (const float4*)W;
  float4* Wl = (float4*)Ws;
#pragma unroll
  for (int it = 0; it < 16; ++it) Wl[it * 256 + tid] = Wg[it * 256 + tid];
  int lane = tid & 63;
  int wave = tid >> 6;
  float a1c = a[lane], a2c = a[64 + lane], a3c = a[128 + lane];
  float Wer[8];
#pragma unroll
  for (int k = 0; k < 8; ++k) Wer[k] = We[k * 64 + lane];
  __syncthreads();
  int rbase = blockIdx.x * 16 + wave * 4;
  const float* hr0 = h + (long)(rbase + 0) * FIN;
  const float* hr1 = h + (long)(rbase + 1) * FIN;
  const float* hr2 = h + (long)(rbase + 2) * FIN;
  const float* hr3 = h + (long)(rbase + 3) * FIN;
  float acc0 = 0.f, acc1 = 0.f, acc2 = 0.f, acc3 = 0.f;
#pragma unroll 2
  for (int k = 0; k < FIN; k += 4) {
    float4 h0 = *(const float4*)(hr0 + k);
    float4 h1 = *(const float4*)(hr1 + k);
    float4 h2 = *(const float4*)(hr2 + k);
    float4 h3 = *(const float4*)(hr3 + k);
#pragma unroll
    for (int t = 0; t < 4; ++t) {
      float w = Ws[(k + t) * 64 + lane];
      float e0 = (t == 0) ? h0.x : (t == 1) ? h0.y : (t == 2) ? h0.z : h0.w;
      float e1 = (t == 0) ? h1.x : (t == 1) ? h1.y : (t == 2) ? h1.z : h1.w;
      float e2 = (t == 0) ? h2.x : (t == 1) ? h2.y : (t == 2) ? h2.z : h2.w;
      float e3 = (t == 0) ? h3.x : (t == 1) ? h3.y : (t == 2) ? h3.z : h3.w;
      acc0 = __builtin_fmaf(e0, w, acc0);
      acc1 = __builtin_fmaf(e1, w, acc1);
      acc2 = __builtin_fmaf(e2, w, acc2);
      acc3 = __builtin_fmaf(e3, w, acc3);
    }
  }
#pragma unroll
  for (int rr = 0; rr < 4; ++rr) {
    int r = rbase + rr;
    float acc = (rr == 0) ? acc0 : (rr == 1) ? acc1 : (rr == 2) ? acc2 : acc3;
    float4 e0 = *(const float4*)(edge + r * 8);
    float4 e1 = *(const float4*)(edge + r * 8 + 4);
    float aedge = e0.x * Wer[0] + e0.y * Wer[1] + e0.z * Wer[2] +
                  e0.w * Wer[3] + e1.x * Wer[4] + e1.y * Wer[5] +
                  e1.z * Wer[6] + e1.w * Wer[7];
    float ps = acc * a1c + aedge * a3c;
    float pd = acc * a2c;
#pragma unroll
    for (int off = 32; off >= 1; off >>= 1) {
      ps += __shfl_xor(ps, off);
      pd += __shfl_xor(pd, off);
    }
    // tiled layout: whT[(j>>5)*2048 + fout*32 + (j&31)]
    whT[((long)(r >> 5)) * 2048 + lane * 32 + (r & 31)] = f2bf(acc);
    if (lane == 0) {
      srcv[r] = ps;
      dstv[r] = pd;
    }
  }
}

// ---------------- Kernel 1b: global max of dst ----------------------------
__global__ __launch_bounds__(256) void k1b_dstmax(const float* __restrict__ dstv,
                                                  float* __restrict__ dmax) {
  int tid = threadIdx.x;
  float m = -1e30f;
  for (int k = tid; k < NROW; k += 256) m = fmaxf(m, dstv[k]);
#pragma unroll
  for (int off = 32; off >= 1; off >>= 1) m = fmaxf(m, __shfl_xor(m, off));
  __shared__ float red[4];
  if ((tid & 63) == 0) red[tid >> 6] = m;
  __syncthreads();
  if (tid == 0) dmax[0] = fmaxf(fmaxf(red[0], red[1]), fmaxf(red[2], red[3]));
}

// ---- Kernel 2: fused masked-softmax-weight x Wh (MFMA), full-row blocks ---
// Block = 16 rows x all 8192 cols. Waves INTERLEAVE at 32-col granularity
// (wave w owns col-blocks c with c%4==w): per step the 4 waves read one
// contiguous 512B span per row -> 16 dense DRAM streams/block (was 64).
// Partials combined in LDS; div+ELU+store fused.
struct AdjB {
  v4i a0, a1;
};
struct DWB {
  float4 d0, d1;
  v8s b0, b1, b2, b3;
};

static __device__ __forceinline__ void adjload(AdjB& A,
                                               const int* __restrict__ adj,
                                               long rowbase, int g, int jj) {
  const v4i* ap = (const v4i*)(adj + rowbase + jj + g * 8);
  A.a0 = *ap;
  A.a1 = *(ap + 1);
}

static __device__ __forceinline__ void dwload(DWB& D,
                                              const float* __restrict__ dstv,
                                              const unsigned short* __restrict__ whT,
                                              int g, int m, int jj) {
  const float* dp = dstv + jj + g * 8;
  D.d0 = *(const float4*)dp;
  D.d1 = *(const float4*)(dp + 4);
  // tiled whT: tile (jj>>5) is 2048 shorts; fragment c at +c*512; each of
  // the 4 loads below covers a contiguous 1KB across the wave's 64 lanes.
  const unsigned short* wp = whT + ((long)(jj >> 5)) * 2048 + m * 32 + g * 8;
  D.b0 = *(const v8s*)(wp + 0);
  D.b1 = *(const v8s*)(wp + 512);
  D.b2 = *(const v8s*)(wp + 1024);
  D.b3 = *(const v8s*)(wp + 1536);
}

static __device__ __forceinline__ void computestep(const AdjB& A, const DWB& D,
                                                   float sv, float M2, v4f& a0,
                                                   v4f& a1, v4f& a2, v4f& a3,
                                                   float& ssum) {
  v8s aw;
#define WCALC(adji, dsti, slot)                                 \
  {                                                             \
    float x = sv + (dsti);                                      \
    float lr = fmaxf(x, ALPHA * x);                             \
    float w = exp2f(__builtin_fmaf(lr, LOG2E, -M2));            \
    unsigned short wb = ((adji) > 0) ? f2bf(w) : (unsigned short)0; \
    ssum += bf2f(wb);                                           \
    aw[slot] = (short)wb;                                       \
  }
  WCALC(A.a0[0], D.d0.x, 0)
  WCALC(A.a0[1], D.d0.y, 1)
  WCALC(A.a0[2], D.d0.z, 2)
  WCALC(A.a0[3], D.d0.w, 3)
  WCALC(A.a1[0], D.d1.x, 4)
  WCALC(A.a1[1], D.d1.y, 5)
  WCALC(A.a1[2], D.d1.z, 6)
  WCALC(A.a1[3], D.d1.w, 7)
#undef WCALC
  a0 = __builtin_amdgcn_mfma_f32_16x16x32_bf16(aw, D.b0, a0, 0, 0, 0);
  a1 = __builtin_amdgcn_mfma_f32_16x16x32_bf16(aw, D.b1, a1, 0, 0, 0);
  a2 = __builtin_amdgcn_mfma_f32_16x16x32_bf16(aw, D.b2, a2, 0, 0, 0);
  a3 = __builtin_amdgcn_mfma_f32_16x16x32_bf16(aw, D.b3, a3, 0, 0, 0);
}

__global__ __launch_bounds__(256) void k2_attn(
    const int* __restrict__ adj, const float* __restrict__ srcg,
    const float* __restrict__ dstv, const float* __restrict__ dmax,
    const unsigned short* __restrict__ whT, float* __restrict__ out) {
  __shared__ float nums[4][16][68];  // pad 64->68: conflict-free writes
  __shared__ float dens[4][16];
  int tid = threadIdx.x;
  int lane = tid & 63;
  int wave = tid >> 6;
  int rtile = blockIdx.x * 16;
  int m = lane & 15;
  int g = lane >> 4;
  int row = rtile + m;
  long rowbase = (long)row * NROW;
  float sv = srcg[row];
  float dm = dmax[0];
  float xm = sv + dm;
  float M2 = fmaxf(xm, ALPHA * xm) * LOG2E;
  v4f a0 = {}, a1 = {}, a2 = {}, a3 = {};
  float ssum = 0.f;
  AdjB A0, A1;
  DWB D0, D1;
  // wave-interleaved column block: step t -> cols [(t*4+wave)*32, +32)
#define JJ(t) (((t) * NWAVES + wave) * 32)
  adjload(A0, adj, rowbase, g, JJ(0));
  adjload(A1, adj, rowbase, g, JJ(1));
  dwload(D0, dstv, whT, g, m, JJ(0));
  for (int t = 0; t < NSTEP2; t += 2) {
    dwload(D1, dstv, whT, g, m, JJ(t + 1));
    computestep(A0, D0, sv, M2, a0, a1, a2, a3, ssum);
    if (t + 2 < NSTEP2) {
      adjload(A0, adj, rowbase, g, JJ(t + 2));
      dwload(D0, dstv, whT, g, m, JJ(t + 2));
    }
    computestep(A1, D1, sv, M2, a0, a1, a2, a3, ssum);
    if (t + 3 < NSTEP2)
      adjload(A1, adj, rowbase, g, JJ(t + 3));
  }
#undef JJ
  // row-sum across the 4 k-groups
  ssum += __shfl_xor(ssum, 16);
  ssum += __shfl_xor(ssum, 32);
  if (g == 0) dens[wave][m] = ssum;
  // D layout: row=(g*4+r), col=ct*16+m
#pragma unroll
  for (int r = 0; r < 4; ++r) {
    nums[wave][g * 4 + r][0 + m] = a0[r];
    nums[wave][g * 4 + r][16 + m] = a1[r];
    nums[wave][g * 4 + r][32 + m] = a2[r];
    nums[wave][g * 4 + r][48 + m] = a3[r];
  }
  __syncthreads();
  // combine 4 wave-partials, divide, ELU, store: thread -> 4 consecutive cols
  int orow = tid >> 4;
  int ocol = (tid & 15) * 4;
  float4 n = {0.f, 0.f, 0.f, 0.f};
  float den = 0.f;
#pragma unroll
  for (int w = 0; w < 4; ++w) {
    float4 v = *(const float4*)&nums[w][orow][ocol];
    n.x += v.x;
    n.y += v.y;
    n.z += v.z;
    n.w += v.w;
    den += dens[w][orow];
  }
  float rd = 1.0f / den;
  float4 o;
  o.x = n.x * rd;
  o.y = n.y * rd;
  o.z = n.z * rd;
  o.w = n.w * rd;
  o.x = o.x > 0.f ? o.x : (__expf(o.x) - 1.0f);
  o.y = o.y > 0.f ? o.y : (__expf(o.y) - 1.0f);
  o.z = o.z > 0.f ? o.z : (__expf(o.z) - 1.0f);
  o.w = o.w > 0.f ? o.w : (__expf(o.w) - 1.0f);
  *(float4*)(out + (long)(rtile + orow) * FOUT + ocol) = o;
}

extern "C" void kernel_launch(void* const* d_in, const int* in_sizes, int n_in,
                              void* d_out, int out_size, void* d_ws,
                              size_t ws_size, hipStream_t stream) {
  const float* h = (const float*)d_in[0];
  const float* edge = (const float*)d_in[1];
  const int* adj = (const int*)d_in[2];
  const float* W = (const float*)d_in[3];
  const float* a = (const float*)d_in[4];
  const float* We = (const float*)d_in[5];
  float* out = (float*)d_out;
  char* ws = (char*)d_ws;
  unsigned short* whT = (unsigned short*)ws;           // 1 MB (tiled)
  float* srcv = (float*)(ws + 1048576);                // 32 KB
  float* dstv = (float*)(ws + 1081344);                // 32 KB
  float* dmax = (float*)(ws + 1114112);                // pad to 256B
  hipLaunchKernelGGL(k1_proj, dim3(512), dim3(256), 0, stream, h, edge, W, a,
                     We, whT, srcv, dstv);
  hipLaunchKernelGGL(k1b_dstmax, dim3(1), dim3(256), 0, stream, dstv, dmax);
  hipLaunchKernelGGL(k2_attn, dim3(512), dim3(256), 0, stream, adj, srcv, dstv,
                     dmax, whT, out);
}

// Round 15
// 411.905 us; speedup vs baseline: 1.0986x; 1.0157x over previous
//
#include <hip/hip_runtime.h>

typedef float v4f __attribute__((ext_vector_type(4)));
typedef short v8s __attribute__((ext_vector_type(8)));
typedef int v4i __attribute__((ext_vector_type(4)));

#define ALPHA 0.2f
#define LOG2E 1.44269504088896340736f
#define NROW 8192
#define FIN 256
#define FOUT 64
#define NWAVES 8
#define NSTEP2 (NROW / 32 / NWAVES) /* 32 */

static __device__ __forceinline__ unsigned short f2bf(float f) {
  unsigned int u = __builtin_bit_cast(unsigned int, f);
  u += 0x7fff + ((u >> 16) & 1);
  return (unsigned short)(u >> 16);
}
static __device__ __forceinline__ float bf2f(unsigned short s) {
  unsigned int u = ((unsigned int)s) << 16;
  return __builtin_bit_cast(float, u);
}

// ---- Kernel 1: Wh = h@W -> whT tiled [j/32][64][32] bf16; src, dst --------
__global__ __launch_bounds__(256) void k1_proj(
    const float* __restrict__ h, const float* __restrict__ edge,
    const float* __restrict__ W, const float* __restrict__ a,
    const float* __restrict__ We, unsigned short* __restrict__ whT,
    float* __restrict__ srcv, float* __restrict__ dstv) {
  __shared__ float Ws[FIN * FOUT];
  int tid = threadIdx.x;
  const float4* Wg = (const float4*)W;
  float4* Wl = (float4*)Ws;
#pragma unroll
  for (int it = 0; it < 16; ++it) Wl[it * 256 + tid] = Wg[it * 256 + tid];
  int lane = tid & 63;
  int wave = tid >> 6;
  float a1c = a[lane], a2c = a[64 + lane], a3c = a[128 + lane];
  float Wer[8];
#pragma unroll
  for (int k = 0; k < 8; ++k) Wer[k] = We[k * 64 + lane];
  __syncthreads();
  int rbase = blockIdx.x * 16 + wave * 4;
  const float* hr0 = h + (long)(rbase + 0) * FIN;
  const float* hr1 = h + (long)(rbase + 1) * FIN;
  const float* hr2 = h + (long)(rbase + 2) * FIN;
  const float* hr3 = h + (long)(rbase + 3) * FIN;
  float acc0 = 0.f, acc1 = 0.f, acc2 = 0.f, acc3 = 0.f;
#pragma unroll 2
  for (int k = 0; k < FIN; k += 4) {
    float4 h0 = *(const float4*)(hr0 + k);
    float4 h1 = *(const float4*)(hr1 + k);
    float4 h2 = *(const float4*)(hr2 + k);
    float4 h3 = *(const float4*)(hr3 + k);
#pragma unroll
    for (int t = 0; t < 4; ++t) {
      float w = Ws[(k + t) * 64 + lane];
      float e0 = (t == 0) ? h0.x : (t == 1) ? h0.y : (t == 2) ? h0.z : h0.w;
      float e1 = (t == 0) ? h1.x : (t == 1) ? h1.y : (t == 2) ? h1.z : h1.w;
      float e2 = (t == 0) ? h2.x : (t == 1) ? h2.y : (t == 2) ? h2.z : h2.w;
      float e3 = (t == 0) ? h3.x : (t == 1) ? h3.y : (t == 2) ? h3.z : h3.w;
      acc0 = __builtin_fmaf(e0, w, acc0);
      acc1 = __builtin_fmaf(e1, w, acc1);
      acc2 = __builtin_fmaf(e2, w, acc2);
      acc3 = __builtin_fmaf(e3, w, acc3);
    }
  }
#pragma unroll
  for (int rr = 0; rr < 4; ++rr) {
    int r = rbase + rr;
    float acc = (rr == 0) ? acc0 : (rr == 1) ? acc1 : (rr == 2) ? acc2 : acc3;
    float4 e0 = *(const float4*)(edge + r * 8);
    float4 e1 = *(const float4*)(edge + r * 8 + 4);
    float aedge = e0.x * Wer[0] + e0.y * Wer[1] + e0.z * Wer[2] +
                  e0.w * Wer[3] + e1.x * Wer[4] + e1.y * Wer[5] +
                  e1.z * Wer[6] + e1.w * Wer[7];
    float ps = acc * a1c + aedge * a3c;
    float pd = acc * a2c;
#pragma unroll
    for (int off = 32; off >= 1; off >>= 1) {
      ps += __shfl_xor(ps, off);
      pd += __shfl_xor(pd, off);
    }
    // tiled layout: whT[(j>>5)*2048 + fout*32 + (j&31)]
    whT[((long)(r >> 5)) * 2048 + lane * 32 + (r & 31)] = f2bf(acc);
    if (lane == 0) {
      srcv[r] = ps;
      dstv[r] = pd;
    }
  }
}

// ---------------- Kernel 1b: global max of dst ----------------------------
__global__ __launch_bounds__(256) void k1b_dstmax(const float* __restrict__ dstv,
                                                  float* __restrict__ dmax) {
  int tid = threadIdx.x;
  float m = -1e30f;
  for (int k = tid; k < NROW; k += 256) m = fmaxf(m, dstv[k]);
#pragma unroll
  for (int off = 32; off >= 1; off >>= 1) m = fmaxf(m, __shfl_xor(m, off));
  __shared__ float red[4];
  if ((tid & 63) == 0) red[tid >> 6] = m;
  __syncthreads();
  if (tid == 0) dmax[0] = fmaxf(fmaxf(red[0], red[1]), fmaxf(red[2], red[3]));
}

// ---- Kernel 2: fused masked-softmax-weight x Wh (MFMA), full-row blocks ---
// Block = 16 rows x all 8192 cols, 8 WAVES (512 thr) -> 4 waves/SIMD TLP.
// Wave w owns col-blocks c with c%8==w: per step the 8 waves read one
// contiguous 1KB span per row. Partials combined in LDS; div+ELU+store fused.
struct AdjB {
  v4i a0, a1;
};
struct DWB {
  float4 d0, d1;
  v8s b0, b1, b2, b3;
};

static __device__ __forceinline__ void adjload(AdjB& A,
                                               const int* __restrict__ adj,
                                               long rowbase, int g, int jj) {
  const v4i* ap = (const v4i*)(adj + rowbase + jj + g * 8);
  A.a0 = *ap;
  A.a1 = *(ap + 1);
}

static __device__ __forceinline__ void dwload(DWB& D,
                                              const float* __restrict__ dstv,
                                              const unsigned short* __restrict__ whT,
                                              int g, int m, int jj) {
  const float* dp = dstv + jj + g * 8;
  D.d0 = *(const float4*)dp;
  D.d1 = *(const float4*)(dp + 4);
  // tiled whT: tile (jj>>5) is 2048 shorts; fragment c at +c*512; each of
  // the 4 loads below covers a contiguous 1KB across the wave's 64 lanes.
  const unsigned short* wp = whT + ((long)(jj >> 5)) * 2048 + m * 32 + g * 8;
  D.b0 = *(const v8s*)(wp + 0);
  D.b1 = *(const v8s*)(wp + 512);
  D.b2 = *(const v8s*)(wp + 1024);
  D.b3 = *(const v8s*)(wp + 1536);
}

static __device__ __forceinline__ void computestep(const AdjB& A, const DWB& D,
                                                   float sv, float M2, v4f& a0,
                                                   v4f& a1, v4f& a2, v4f& a3,
                                                   float& ssum) {
  v8s aw;
#define WCALC(adji, dsti, slot)                                 \
  {                                                             \
    float x = sv + (dsti);                                      \
    float lr = fmaxf(x, ALPHA * x);                             \
    float w = exp2f(__builtin_fmaf(lr, LOG2E, -M2));            \
    unsigned short wb = ((adji) > 0) ? f2bf(w) : (unsigned short)0; \
    ssum += bf2f(wb);                                           \
    aw[slot] = (short)wb;                                       \
  }
  WCALC(A.a0[0], D.d0.x, 0)
  WCALC(A.a0[1], D.d0.y, 1)
  WCALC(A.a0[2], D.d0.z, 2)
  WCALC(A.a0[3], D.d0.w, 3)
  WCALC(A.a1[0], D.d1.x, 4)
  WCALC(A.a1[1], D.d1.y, 5)
  WCALC(A.a1[2], D.d1.z, 6)
  WCALC(A.a1[3], D.d1.w, 7)
#undef WCALC
  a0 = __builtin_amdgcn_mfma_f32_16x16x32_bf16(aw, D.b0, a0, 0, 0, 0);
  a1 = __builtin_amdgcn_mfma_f32_16x16x32_bf16(aw, D.b1, a1, 0, 0, 0);
  a2 = __builtin_amdgcn_mfma_f32_16x16x32_bf16(aw, D.b2, a2, 0, 0, 0);
  a3 = __builtin_amdgcn_mfma_f32_16x16x32_bf16(aw, D.b3, a3, 0, 0, 0);
}

__global__ __launch_bounds__(512) void k2_attn(
    const int* __restrict__ adj, const float* __restrict__ srcg,
    const float* __restrict__ dstv, const float* __restrict__ dmax,
    const unsigned short* __restrict__ whT, float* __restrict__ out) {
  __shared__ float nums[NWAVES][16][68];  // pad 64->68: conflict-free writes
  __shared__ float dens[NWAVES][16];
  int tid = threadIdx.x;
  int lane = tid & 63;
  int wave = tid >> 6;
  int rtile = blockIdx.x * 16;
  int m = lane & 15;
  int g = lane >> 4;
  int row = rtile + m;
  long rowbase = (long)row * NROW;
  float sv = srcg[row];
  float dm = dmax[0];
  float xm = sv + dm;
  float M2 = fmaxf(xm, ALPHA * xm) * LOG2E;
  v4f a0 = {}, a1 = {}, a2 = {}, a3 = {};
  float ssum = 0.f;
  AdjB A0, A1;
  DWB D0, D1;
  // wave-interleaved column block: step t -> cols [(t*8+wave)*32, +32)
#define JJ(t) (((t) * NWAVES + wave) * 32)
  adjload(A0, adj, rowbase, g, JJ(0));
  adjload(A1, adj, rowbase, g, JJ(1));
  dwload(D0, dstv, whT, g, m, JJ(0));
  for (int t = 0; t < NSTEP2; t += 2) {
    dwload(D1, dstv, whT, g, m, JJ(t + 1));
    computestep(A0, D0, sv, M2, a0, a1, a2, a3, ssum);
    if (t + 2 < NSTEP2) {
      adjload(A0, adj, rowbase, g, JJ(t + 2));
      dwload(D0, dstv, whT, g, m, JJ(t + 2));
    }
    computestep(A1, D1, sv, M2, a0, a1, a2, a3, ssum);
    if (t + 3 < NSTEP2)
      adjload(A1, adj, rowbase, g, JJ(t + 3));
  }
#undef JJ
  // row-sum across the 4 k-groups
  ssum += __shfl_xor(ssum, 16);
  ssum += __shfl_xor(ssum, 32);
  if (g == 0) dens[wave][m] = ssum;
  // D layout: row=(g*4+r), col=ct*16+m
#pragma unroll
  for (int r = 0; r < 4; ++r) {
    nums[wave][g * 4 + r][0 + m] = a0[r];
    nums[wave][g * 4 + r][16 + m] = a1[r];
    nums[wave][g * 4 + r][32 + m] = a2[r];
    nums[wave][g * 4 + r][48 + m] = a3[r];
  }
  __syncthreads();
  // combine 8 wave-partials, divide, ELU, store: thread -> 2 consecutive cols
  int orow = tid >> 5;           // 512 thr / 16 rows = 32 thr/row
  int ocol = (tid & 31) * 2;     // 2 cols each
  float nx = 0.f, ny = 0.f;
  float den = 0.f;
#pragma unroll
  for (int w = 0; w < NWAVES; ++w) {
    float2 v = *(const float2*)&nums[w][orow][ocol];
    nx += v.x;
    ny += v.y;
    den += dens[w][orow];
  }
  float rd = 1.0f / den;
  float2 o;
  o.x = nx * rd;
  o.y = ny * rd;
  o.x = o.x > 0.f ? o.x : (__expf(o.x) - 1.0f);
  o.y = o.y > 0.f ? o.y : (__expf(o.y) - 1.0f);
  *(float2*)(out + (long)(rtile + orow) * FOUT + ocol) = o;
}

extern "C" void kernel_launch(void* const* d_in, const int* in_sizes, int n_in,
                              void* d_out, int out_size, void* d_ws,
                              size_t ws_size, hipStream_t stream) {
  const float* h = (const float*)d_in[0];
  const float* edge = (const float*)d_in[1];
  const int* adj = (const int*)d_in[2];
  const float* W = (const float*)d_in[3];
  const float* a = (const float*)d_in[4];
  const float* We = (const float*)d_in[5];
  float* out = (float*)d_out;
  char* ws = (char*)d_ws;
  unsigned short* whT = (unsigned short*)ws;           // 1 MB (tiled)
  float* srcv = (float*)(ws + 1048576);                // 32 KB
  float* dstv = (float*)(ws + 1081344);                // 32 KB
  float* dmax = (float*)(ws + 1114112);                // pad to 256B
  hipLaunchKernelGGL(k1_proj, dim3(512), dim3(256), 0, stream, h, edge, W, a,
                     We, whT, srcv, dstv);
  hipLaunchKernelGGL(k1b_dstmax, dim3(1), dim3(256), 0, stream, dstv, dmax);
  hipLaunchKernelGGL(k2_attn, dim3(512), dim3(512), 0, stream, adj, srcv, dstv,
                     dmax, whT, out);
}